// Round 1
// 145.556 us; speedup vs baseline: 1.2669x; 1.2669x over previous
//
#include <hip/hip_runtime.h>

#define BB   256
#define II   1152
#define OO   10
#define DOUT 16

using h2 = __fp16 __attribute__((ext_vector_type(2)));
using h4 = __fp16 __attribute__((ext_vector_type(4)));
using h8 = __fp16 __attribute__((ext_vector_type(8)));
#define H2V(v, a, b) __builtin_shufflevector((v), (v), (a), (b))
#define FD(a, b, c)  __builtin_amdgcn_fdot2((a), (b), (c), false)   // v_dot2_f32_f16

typedef __attribute__((address_space(3))) uint32_t lds_u32_t;
typedef __attribute__((address_space(1))) const uint32_t glb_u32_t;

// width-16 global->LDS DMA: LDS dest = uniform base + lane*16 (linear), global
// source is per-lane. No VGPR round-trip, no cvt (w pre-converted to f16).
__device__ __forceinline__ void dma16(const __fp16* g, __fp16* l) {
  __builtin_amdgcn_global_load_lds((glb_u32_t*)g, (lds_u32_t*)l, 16, 0, 0);
}

// Cross-lane reduce over the 8 dsub lanes: xor1/xor2 on VALU (DPP), xor4 on DS.
__device__ __forceinline__ float dpp_add_xor1(float v) {
  int r = __builtin_amdgcn_mov_dpp(__float_as_int(v), 0xB1, 0xF, 0xF, true);
  return v + __int_as_float(r);
}
__device__ __forceinline__ float dpp_add_xor2(float v) {
  int r = __builtin_amdgcn_mov_dpp(__float_as_int(v), 0x4E, 0xF, 0xF, true);
  return v + __int_as_float(r);
}
__device__ __forceinline__ float swz_add_xor4(float v) {
  int r = __builtin_amdgcn_ds_swizzle(__float_as_int(v), 0x101F);
  return v + __int_as_float(r);
}

// One-time f32->f16 conversion with layout permute.
//   w:  [O][I][16][8] f32  ->  w16: [I][12][16][8] f16 (o padded 10->12 so each
//       per-i tile is 3072 B = exactly 3 width-16 wave-DMAs; pad rows never read)
//   x:  [B][I][8] f32      ->  x16: [B][I][8] f16 (rtz, same rounding as the old
//       in-loop cvt_pkrtz -> numerics unchanged)
__global__ __launch_bounds__(256) void convert_kernel(
    const float* __restrict__ x, const float* __restrict__ w,
    __fp16* __restrict__ x16, __fp16* __restrict__ w16)
{
  const int bid = blockIdx.x;
  if (bid < 2880) {                       // w part: 11520 rows x 64 float2
    const int t = bid * 256 + threadIdx.x;
    const int e = t & 63;
    const int r = t >> 6;                 // r = o*II + i
    const int o = r / II;
    const int i = r - o * II;
    const float2 v2 = *(const float2*)(w + (size_t)r * 128 + e * 2);
    *(h2*)(w16 + ((size_t)i * 12 + o) * 128 + e * 2) =
        __builtin_amdgcn_cvt_pkrtz(v2.x, v2.y);
  } else {                                // x part: 589824 threads x 4 floats
    const size_t t = (size_t)(bid - 2880) * 256 + threadIdx.x;
    const float4 v4 = *(const float4*)(x + t * 4);
    const h2 a = __builtin_amdgcn_cvt_pkrtz(v4.x, v4.y);
    const h2 c = __builtin_amdgcn_cvt_pkrtz(v4.z, v4.w);
    *(h4*)(x16 + t * 4) = __builtin_shufflevector(a, c, 0, 1, 2, 3);
  }
}

// Pass kernel, barrier-free main loop.
// Wave = 8 b x 9 i, block = 4 waves (32 b, same 36-i group). Grid = 32 icg x 32 bg
// = 1024 blocks; icg fast (stride-32 co-sharers => same XCD => L2-local w16).
// Per-wave triple-buffered 3 KB w-tiles in LDS, staged by global_load_lds DMA.
// Exactly 4 VMEM ops issue per iter (3 DMA + 1 x row), so vmcnt(4) at iter top
// == "tile ii landed, tile ii+1 still in flight" (T4 counted-wait recipe).
template<int K>
__global__ __launch_bounds__(256, 4) void pass_kernel(
    const __fp16* __restrict__ x16,  // f16 [B][I][8]
    const __fp16* __restrict__ w16,  // f16 [I][12][16][8]
    const float* __restrict__ V,     // f32 [B][O][16]
    float* __restrict__ plane)       // f32 [B][O][16] accumulator (pre-zeroed)
{
  const int tid  = threadIdx.x;
  const int lane = tid & 63;
  const int wv   = tid >> 6;
  const int dsub = lane & 7;          // d-pair index (d = 2*dsub + dlo)
  const int bl   = lane >> 3;         // batch-in-wave (8)
  const int icg  = blockIdx.x & 31;   // i-group (4 wave-chunks of 9)
  const int bg   = blockIdx.x >> 5;   // 32 groups of 8 b
  const int b    = bg * 8 + bl;
  const int i0   = (icg * 4 + wv) * 9;

  __shared__ __fp16 wt[4][3 * 1536];  // per-wave 3 bufs x 3072 B = 36.9 KB total
  __fp16* const wbuf = wt[wv];

  float Vr[OO][2];
  if (K >= 1) {
#pragma unroll
    for (int o = 0; o < OO; ++o) {
      const float2 v2 = *(const float2*)(V + ((size_t)b * OO + o) * DOUT + dsub * 2);
      Vr[o][0] = v2.x; Vr[o][1] = v2.y;
    }
  }

  float s[OO][2];
#pragma unroll
  for (int o = 0; o < OO; ++o) { s[o][0] = 0.f; s[o][1] = 0.f; }

  #define STAGE(i_, ofs_)                                                      \
    {                                                                          \
      const __fp16* gp = w16 + (size_t)(i_) * 1536 + lane * 8;                 \
      dma16(gp,        wbuf + (ofs_));                                         \
      dma16(gp + 512,  wbuf + (ofs_) + 512);                                   \
      dma16(gp + 1024, wbuf + (ofs_) + 1024);                                  \
    }

  const __fp16* xrow = x16 + ((size_t)b * II + i0) * 8;

  // prologue: issue group(i0) then group(i0+1); keep the two groups ordered
  STAGE(i0, 0)
  h8 xq = *(const h8*)(xrow);
  asm volatile("" ::: "memory");
  STAGE(i0 + 1, 1536)
  h8 xn = *(const h8*)(xrow + 8);

  int cur = 0;
#pragma unroll 1
  for (int ii = 0; ii < 9; ++ii) {
    // wait: everything except the newest 4 VMEM ops (= next tile's group)
    asm volatile("s_waitcnt vmcnt(4)" ::: "memory");
    __builtin_amdgcn_sched_barrier(0);

    const __fp16* wtb = wbuf + cur * 1536;
    const h2 xq0 = H2V(xq, 0, 1), xq1 = H2V(xq, 2, 3);
    const h2 xq2 = H2V(xq, 4, 5), xq3 = H2V(xq, 6, 7);

    float xh[OO][2];
    float t[OO];
#pragma unroll
    for (int o = 0; o < OO; ++o) {
      const __fp16* cp = wtb + (o * 16 + dsub * 2) * 8;  // 16 B-aligned
      const h8 wa = *(const h8*)(cp);        // d even: 8 c's
      const h8 wb = *(const h8*)(cp + 8);    // d odd:  8 c's
      xh[o][0] = FD(H2V(wa, 0, 1), xq0, FD(H2V(wa, 2, 3), xq1,
                 FD(H2V(wa, 4, 5), xq2, FD(H2V(wa, 6, 7), xq3, 0.f))));
      xh[o][1] = FD(H2V(wb, 0, 1), xq0, FD(H2V(wb, 2, 3), xq1,
                 FD(H2V(wb, 4, 5), xq2, FD(H2V(wb, 6, 7), xq3, 0.f))));
      if (K >= 1)
        t[o] = Vr[o][0] * xh[o][0] + Vr[o][1] * xh[o][1];
    }

    if (K == 0) {
#pragma unroll
      for (int o = 0; o < OO; ++o) { s[o][0] += xh[o][0]; s[o][1] += xh[o][1]; }
    } else {
#pragma unroll
      for (int o = 0; o < OO; ++o) {   // reduce over the 8 dsub lanes
        t[o] = dpp_add_xor1(t[o]);
        t[o] = dpp_add_xor2(t[o]);
        t[o] = swz_add_xor4(t[o]);
      }
      float sum = 0.f;
#pragma unroll
      for (int o = 0; o < OO; ++o) { t[o] = __expf(t[o]); sum += t[o]; }
      const float inv = __builtin_amdgcn_rcpf(sum);
#pragma unroll
      for (int o = 0; o < OO; ++o) {
        const float c = t[o] * inv;
        s[o][0] += c * xh[o][0];
        s[o][1] += c * xh[o][1];
      }
    }

    // issue tile(ii+2): clamped re-stage on last iters keeps VMEM count uniform
    const int inx = (ii < 7) ? (i0 + ii + 2) : (i0 + 8);
    int nbuf = cur - 1; if (nbuf < 0) nbuf += 3;   // (cur+2) % 3
    STAGE(inx, nbuf * 1536)
    xq = xn;
    xn = *(const h8*)(x16 + ((size_t)b * II + inx) * 8);

    cur += 1; if (cur == 3) cur = 0;
  }
  #undef STAGE

  if (K == 0) {
#pragma unroll
    for (int o = 0; o < OO; ++o) { s[o][0] *= 0.1f; s[o][1] *= 0.1f; }
  }

  // drain this wave's DMAs, then reuse the (dead) w-buffers for the cross-wave
  // reduce. Each wave writes ONLY its own LDS region (no cross-wave DMA race).
  asm volatile("s_waitcnt vmcnt(0)" ::: "memory");
  if (wv != 0) {
    float* rr = (float*)&wt[wv][0] + bl * 168;   // padded rows: 2-way banks
#pragma unroll
    for (int o = 0; o < OO; ++o)
      *(float2*)&rr[o * 16 + dsub * 2] = make_float2(s[o][0], s[o][1]);
  }
  __syncthreads();
  if (wv == 0) {
    float* out = plane + (size_t)b * (OO * DOUT);
#pragma unroll
    for (int o = 0; o < OO; ++o) {
      float a0 = s[o][0], a1 = s[o][1];
#pragma unroll
      for (int r = 1; r < 4; ++r) {
        const float2 v2 =
            *(const float2*)((const float*)&wt[r][0] + bl * 168 + o * 16 + dsub * 2);
        a0 += v2.x; a1 += v2.y;
      }
      unsafeAtomicAdd(&out[o * 16 + dsub * 2],     a0);
      unsafeAtomicAdd(&out[o * 16 + dsub * 2 + 1], a1);
    }
  }
}

// Squash the accumulated plane, update V / write final output.
template<int K>
__global__ __launch_bounds__(256) void reduce_kernel(
    const float* __restrict__ plane,   // [B*O*DOUT]
    float* __restrict__ V,             // [B*O*DOUT]
    float* __restrict__ out)           // fp32 [B*O*DOUT]
{
  const int idx = blockIdx.x * 256 + threadIdx.x;    // over B*O*DOUT = 40960
  const float s = plane[idx];

  float sq = s * s;
  sq += __shfl_xor(sq, 1);
  sq += __shfl_xor(sq, 2);
  sq += __shfl_xor(sq, 4);
  sq += __shfl_xor(sq, 8);
  const float mag = sqrtf(sq);
  const float v = sq / (1.f + sq) * (s / (mag + 1e-8f));

  if (K == 0)      V[idx] = v;
  else if (K == 1) V[idx] += v;        // b-linearity: t(V0+V1) = t(V0)+t(V1)
  else             out[idx] = v;
}

extern "C" void kernel_launch(void* const* d_in, const int* in_sizes, int n_in,
                              void* d_out, int out_size, void* d_ws, size_t ws_size,
                              hipStream_t stream) {
  const float* x = (const float*)d_in[0];   // fp32 [256,1152,8]
  const float* w = (const float*)d_in[1];   // fp32 [10,1152,16,8]
  float* out = (float*)d_out;               // fp32 [256,10,16]

  const size_t P = (size_t)BB * OO * DOUT;  // 40960 floats per plane
  float* s0 = (float*)d_ws;                 // 3 accumulator planes + V
  float* s1 = s0 + P;
  float* s2 = s1 + P;
  float* V  = s2 + P;
  __fp16* x16 = (__fp16*)(V + P);                  // 4.72 MB
  __fp16* w16 = x16 + (size_t)BB * II * 8;         // 3.54 MB (o-padded tiles)

  hipMemsetAsync(s0, 0, 3 * P * sizeof(float), stream);
  convert_kernel<<<5184, 256, 0, stream>>>(x, w, x16, w16);

  const int pg = 1024;                      // 32 icg (fast) x 32 bg; all-resident
  const int rg = (int)(P / 256);            // 160 blocks

  pass_kernel<0><<<pg, 256, 0, stream>>>(x16, w16, V, s0);
  reduce_kernel<0><<<rg, 256, 0, stream>>>(s0, V, out);
  pass_kernel<1><<<pg, 256, 0, stream>>>(x16, w16, V, s1);
  reduce_kernel<1><<<rg, 256, 0, stream>>>(s1, V, out);
  pass_kernel<2><<<pg, 256, 0, stream>>>(x16, w16, V, s2);
  reduce_kernel<2><<<rg, 256, 0, stream>>>(s2, V, out);
}